// Round 2
// baseline (282.674 us; speedup 1.0000x reference)
//
#include <hip/hip_runtime.h>
#include <stdint.h>

// MLP_tcnn: x(524288x64) -> [W0 64x128 relu] -> [W1..W4 128x128 relu] -> [W5 128x16] + bias
// R1 design: per-block 128-sample tile; per layer H_next^T = W^T * H^T with
// mfma_f32_16x16x32_bf16.  A (weights) read DIRECTLY from a lane-ordered global
// image (L1/L2-resident, coalesced 1KB per wave-instruction) -- no LDS staging.
// B = H^T sample-major in 32KB LDS (XOR-swizzled, bank-uniform b128 reads).
// C written back sample-major as b64 (relu+bf16).  LDS/block = 32KB -> 4 blocks/CU.

typedef __bf16 bf16x8 __attribute__((ext_vector_type(8)));
typedef __bf16 bf16x4 __attribute__((ext_vector_type(4)));
typedef float  floatx4 __attribute__((ext_vector_type(4)));

constexpr int NS   = 524288;   // samples
constexpr int TILE = 128;      // samples per block
constexpr int NBLK = NS / TILE;

// weight image in d_ws, 16B chunks, lane-ordered:
// per layer: blocks of 64 chunks; block = (it*KT + kt); pos-in-block = lane = g*16+l15
//   chunk(lane) = W^T[row = it*16 + l15][k-chunk = kt*4 + g]  (8 contiguous in-feats)
// L0: it 0..7, KT=2 -> 1024 chunks; L1-4: it 0..7, KT=4 -> 2048 each; L5: it=0, KT=4 -> 256
constexpr int WTOT = 9472;     // 151552 bytes

__global__ void prep_weights(const float* __restrict__ W0, const float* __restrict__ W1,
                             const float* __restrict__ W2, const float* __restrict__ W3,
                             const float* __restrict__ W4, const float* __restrict__ W5,
                             bf16x8* __restrict__ ws) {
  int gid = blockIdx.x * blockDim.x + threadIdx.x;
  if (gid >= WTOT) return;
  const float* Wsrc; int nout, KT, base;
  if (gid < 1024)      { Wsrc = W0; nout = 128; KT = 2; base = 0;    }
  else if (gid < 3072) { Wsrc = W1; nout = 128; KT = 4; base = 1024; }
  else if (gid < 5120) { Wsrc = W2; nout = 128; KT = 4; base = 3072; }
  else if (gid < 7168) { Wsrc = W3; nout = 128; KT = 4; base = 5120; }
  else if (gid < 9216) { Wsrc = W4; nout = 128; KT = 4; base = 7168; }
  else                 { Wsrc = W5; nout = 16;  KT = 4; base = 9216; }
  int id  = gid - base;
  int p   = id & 63;           // lane position
  int l15 = p & 15;
  int g   = p >> 4;
  int blk = id >> 6;
  int kt  = blk % KT;
  int it  = blk / KT;
  int row = it * 16 + l15;     // out-feature (row of W^T)
  int kc  = kt * 4 + g;        // k-chunk (8 in-features)
  bf16x8 v;
#pragma unroll
  for (int j = 0; j < 8; ++j)
    v[j] = (__bf16)Wsrc[(8 * kc + j) * nout + row];   // W^T[row][8kc+j] = W[8kc+j][row]
  ws[gid] = v;
}

__device__ __forceinline__ void zero_acc(floatx4 acc[4][4]) {
  floatx4 z = {0.f, 0.f, 0.f, 0.f};
#pragma unroll
  for (int i = 0; i < 4; ++i)
#pragma unroll
    for (int j = 0; j < 4; ++j) acc[i][j] = z;
}

// one 64-out x 64-sample quadrant; A from global (wg = layer image + m_half offset),
// B from LDS Hbuf.  KT = K/32.
template <int KT>
__device__ __forceinline__ void layer_mm(const bf16x8* __restrict__ wg,
                                         const bf16x8* Hb, floatx4 acc[4][4],
                                         int n_base, int l15, int g, int lane) {
#pragma unroll
  for (int kt = 0; kt < KT; ++kt) {
    const int cx = (kt * 4 + g) ^ (l15 & 7);
    bf16x8 a[4], b[4];
#pragma unroll
    for (int i = 0; i < 4; ++i) a[i] = wg[((i * KT + kt) << 6) + lane];   // coalesced 1KB
#pragma unroll
    for (int i = 0; i < 4; ++i) b[i] = Hb[(n_base + 16 * i + l15) * 16 + cx];
#pragma unroll
    for (int ot = 0; ot < 4; ++ot)
#pragma unroll
      for (int nt = 0; nt < 4; ++nt)
        acc[ot][nt] = __builtin_amdgcn_mfma_f32_16x16x32_bf16(a[ot], b[nt], acc[ot][nt], 0, 0, 0);
  }
}

// C-frag (col=sample=l15, rows 4g..4g+3 out-feats) -> relu -> bf16 -> H sample-major
__device__ __forceinline__ void write_h(bf16x4* H8, const floatx4 acc[4][4],
                                        int m_base, int n_base, int l15, int g) {
#pragma unroll
  for (int ot = 0; ot < 4; ++ot) {
    int ob    = m_base + 16 * ot + 4 * g;                        // out-feature base
    int phys8 = (((ob >> 3) ^ (l15 & 7)) << 1) | ((ob >> 2) & 1);
#pragma unroll
    for (int nt = 0; nt < 4; ++nt) {
      int s = n_base + 16 * nt + l15;                            // sample row
      floatx4 v = acc[ot][nt];
      bf16x4 h;
      h[0] = (__bf16)fmaxf(v[0], 0.0f);
      h[1] = (__bf16)fmaxf(v[1], 0.0f);
      h[2] = (__bf16)fmaxf(v[2], 0.0f);
      h[3] = (__bf16)fmaxf(v[3], 0.0f);
      H8[s * 32 + phys8] = h;
    }
  }
}

__global__ void __launch_bounds__(256, 4) mlp_kernel(const float* __restrict__ x,
                                                     const float* __restrict__ bias,
                                                     const bf16x8* __restrict__ wimg,
                                                     float* __restrict__ out) {
  __shared__ bf16x8 Hbuf[TILE * 16];   // 32KB: sample-major rows, 16 chunk slots, XOR-swizzled

  const int t    = threadIdx.x;
  const int lane = t & 63;
  const int w    = t >> 6;
  const int l15  = lane & 15;
  const int g    = lane >> 4;
  const int m_half = w & 1;
  const int m_base = m_half * 64;      // out-feature quadrant
  const int n_base = (w >> 1) * 64;    // sample quadrant
  const int tile = blockIdx.x;

  // stage x tile -> Hbuf (fp32 -> bf16), one 16B chunk (8 feats of one sample) per iter
  const float* xt = x + (size_t)tile * TILE * 64;
#pragma unroll
  for (int i = 0; i < 4; ++i) {
    int f2 = t + 256 * i;              // chunk id 0..1023
    int s = f2 >> 3, c = f2 & 7;
    const floatx4* src = (const floatx4*)(xt + f2 * 8);
    floatx4 lo = src[0], hi = src[1];
    bf16x8 v;
    v[0] = (__bf16)lo[0]; v[1] = (__bf16)lo[1]; v[2] = (__bf16)lo[2]; v[3] = (__bf16)lo[3];
    v[4] = (__bf16)hi[0]; v[5] = (__bf16)hi[1]; v[6] = (__bf16)hi[2]; v[7] = (__bf16)hi[3];
    Hbuf[s * 16 + (c ^ (s & 7))] = v;
  }
  __syncthreads();

  floatx4 acc[4][4];

  // ---- layer 0: K=64 ----
  zero_acc(acc);
  layer_mm<2>(wimg + m_half * 512, Hbuf, acc, n_base, l15, g, lane);
  __syncthreads();                                   // all Hbuf reads done (WAR)
  write_h((bf16x4*)Hbuf, acc, m_base, n_base, l15, g);
  __syncthreads();                                   // H(l+1) visible (RAW)

  // ---- layers 1..4: K=128 ----
  constexpr int WOFF[5] = {1024, 3072, 5120, 7168, 9216};
#pragma unroll
  for (int l = 0; l < 4; ++l) {
    zero_acc(acc);
    layer_mm<4>(wimg + WOFF[l] + m_half * 1024, Hbuf, acc, n_base, l15, g, lane);
    __syncthreads();
    write_h((bf16x4*)Hbuf, acc, m_base, n_base, l15, g);
    __syncthreads();
  }

  // ---- layer 5: M=16, K=128, no relu, + bias, store fp32 ----
  floatx4 a5[2];
  {
    floatx4 z = {0.f, 0.f, 0.f, 0.f};
    a5[0] = z; a5[1] = z;
  }
  const int n5 = w * 32;               // each wave: 32 samples, all 16 out-features
#pragma unroll
  for (int kt = 0; kt < 4; ++kt) {
    int cx = (kt * 4 + g) ^ (l15 & 7);
    bf16x8 a = wimg[9216 + (kt << 6) + lane];        // W5^T, coalesced
#pragma unroll
    for (int nt = 0; nt < 2; ++nt) {
      bf16x8 b = Hbuf[(n5 + 16 * nt + l15) * 16 + cx];
      a5[nt] = __builtin_amdgcn_mfma_f32_16x16x32_bf16(a, b, a5[nt], 0, 0, 0);
    }
  }
  floatx4 bv = *(const floatx4*)(bias + 4 * g);
  floatx4* outv = (floatx4*)out;
#pragma unroll
  for (int nt = 0; nt < 2; ++nt) {
    int s = tile * TILE + n5 + 16 * nt + l15;
    outv[s * 4 + g] = a5[nt] + bv;     // wave's stores cover contiguous 1KB
  }
}

extern "C" void kernel_launch(void* const* d_in, const int* in_sizes, int n_in,
                              void* d_out, int out_size, void* d_ws, size_t ws_size,
                              hipStream_t stream) {
  (void)in_sizes; (void)n_in; (void)out_size; (void)ws_size;
  const float* x    = (const float*)d_in[0];
  const float* W0   = (const float*)d_in[1];
  const float* W1   = (const float*)d_in[2];
  const float* W2   = (const float*)d_in[3];
  const float* W3   = (const float*)d_in[4];
  const float* W4   = (const float*)d_in[5];
  const float* W5   = (const float*)d_in[6];
  const float* bias = (const float*)d_in[7];
  bf16x8* ws = (bf16x8*)d_ws;   // needs 151552 B

  prep_weights<<<(WTOT + 255) / 256, 256, 0, stream>>>(W0, W1, W2, W3, W4, W5, ws);
  mlp_kernel<<<NBLK, 256, 0, stream>>>(x, bias, (const bf16x8*)ws, (float*)d_out);
}

// Round 3
// 280.431 us; speedup vs baseline: 1.0080x; 1.0080x over previous
//
#include <hip/hip_runtime.h>
#include <stdint.h>

// MLP_tcnn: x(524288x64) -> [W0 64x128 relu] -> [W1..W4 128x128 relu] -> [W5 128x16] + bias
// R3 design: BARRIER-FREE. Each wave owns 32 samples end-to-end: computes all 128
// out-features per layer (acc[8][2]) with mfma_f32_16x16x32_bf16, round-trips H
// through its own private 8KB LDS slice (per-wave DS ops are in-order -> no syncs).
// A (weights) read directly from lane-ordered global image (L1-resident, 32KB/layer,
// coalesced 1KB/instr).  B/H sample-major in LDS, XOR chunk swizzle (bank-uniform).

typedef __bf16 bf16x8 __attribute__((ext_vector_type(8)));
typedef __bf16 bf16x4 __attribute__((ext_vector_type(4)));
typedef float  floatx4 __attribute__((ext_vector_type(4)));

constexpr int NS   = 524288;   // samples
constexpr int TILE = 128;      // samples per block (4 waves x 32)
constexpr int NBLK = NS / TILE;

// weight image in d_ws, 16B chunks, lane-ordered:
// per layer: blocks of 64 chunks; block = (it*KT + kt); pos-in-block = lane = g*16+l15
//   chunk(lane) = W^T[row = it*16 + l15][k-chunk = kt*4 + g]  (8 contiguous in-feats)
// L0: it 0..7, KT=2 -> 1024 chunks; L1-4: it 0..7, KT=4 -> 2048 each; L5: it=0, KT=4 -> 256
constexpr int WTOT = 9472;     // 151552 bytes

__global__ void prep_weights(const float* __restrict__ W0, const float* __restrict__ W1,
                             const float* __restrict__ W2, const float* __restrict__ W3,
                             const float* __restrict__ W4, const float* __restrict__ W5,
                             bf16x8* __restrict__ ws) {
  int gid = blockIdx.x * blockDim.x + threadIdx.x;
  if (gid >= WTOT) return;
  const float* Wsrc; int nout, KT, base;
  if (gid < 1024)      { Wsrc = W0; nout = 128; KT = 2; base = 0;    }
  else if (gid < 3072) { Wsrc = W1; nout = 128; KT = 4; base = 1024; }
  else if (gid < 5120) { Wsrc = W2; nout = 128; KT = 4; base = 3072; }
  else if (gid < 7168) { Wsrc = W3; nout = 128; KT = 4; base = 5120; }
  else if (gid < 9216) { Wsrc = W4; nout = 128; KT = 4; base = 7168; }
  else                 { Wsrc = W5; nout = 16;  KT = 4; base = 9216; }
  int id  = gid - base;
  int p   = id & 63;           // lane position
  int l15 = p & 15;
  int g   = p >> 4;
  int blk = id >> 6;
  int kt  = blk % KT;
  int it  = blk / KT;
  int row = it * 16 + l15;     // out-feature (row of W^T)
  int kc  = kt * 4 + g;        // k-chunk (8 in-features)
  bf16x8 v;
#pragma unroll
  for (int j = 0; j < 8; ++j)
    v[j] = (__bf16)Wsrc[(8 * kc + j) * nout + row];   // W^T[row][8kc+j] = W[8kc+j][row]
  ws[gid] = v;
}

__device__ __forceinline__ void zero_acc(floatx4 acc[8][2]) {
  floatx4 z = {0.f, 0.f, 0.f, 0.f};
#pragma unroll
  for (int i = 0; i < 8; ++i) {
    acc[i][0] = z; acc[i][1] = z;
  }
}

// full 128-out x 32-sample layer for one wave; A from global image, B from the
// wave's private LDS rows.  KT = K/32.
template <int KT>
__device__ __forceinline__ void layer_mm(const bf16x8* __restrict__ wg,
                                         const bf16x8* Hb, floatx4 acc[8][2],
                                         int n_base, int l15, int g, int lane) {
#pragma unroll
  for (int kt = 0; kt < KT; ++kt) {
    const int cx = (kt * 4 + g) ^ (l15 & 7);
    bf16x8 a[8], b[2];
#pragma unroll
    for (int i = 0; i < 8; ++i) a[i] = wg[((i * KT + kt) << 6) + lane];   // coalesced 1KB
    b[0] = Hb[(n_base + l15) * 16 + cx];
    b[1] = Hb[(n_base + 16 + l15) * 16 + cx];
#pragma unroll
    for (int ot = 0; ot < 8; ++ot)
#pragma unroll
      for (int nt = 0; nt < 2; ++nt)
        acc[ot][nt] = __builtin_amdgcn_mfma_f32_16x16x32_bf16(a[ot], b[nt], acc[ot][nt], 0, 0, 0);
  }
}

// C-frag (col=sample=l15, rows 4g..4g+3 out-feats) -> relu -> bf16 -> H sample-major.
// Wave-private: only this wave reads these rows afterwards (per-wave DS order => safe).
__device__ __forceinline__ void write_h(bf16x4* H8, const floatx4 acc[8][2],
                                        int n_base, int l15, int g) {
#pragma unroll
  for (int ot = 0; ot < 8; ++ot) {
    int ob    = 16 * ot + 4 * g;                                 // out-feature base
    int phys8 = (((ob >> 3) ^ (l15 & 7)) << 1) | ((ob >> 2) & 1);
#pragma unroll
    for (int nt = 0; nt < 2; ++nt) {
      int s = n_base + 16 * nt + l15;                            // sample row
      floatx4 v = acc[ot][nt];
      bf16x4 h;
      h[0] = (__bf16)fmaxf(v[0], 0.0f);
      h[1] = (__bf16)fmaxf(v[1], 0.0f);
      h[2] = (__bf16)fmaxf(v[2], 0.0f);
      h[3] = (__bf16)fmaxf(v[3], 0.0f);
      H8[s * 32 + phys8] = h;
    }
  }
}

__global__ void __launch_bounds__(256, 3) mlp_kernel(const float* __restrict__ x,
                                                     const float* __restrict__ bias,
                                                     const bf16x8* __restrict__ wimg,
                                                     float* __restrict__ out) {
  __shared__ bf16x8 Hbuf[TILE * 16];   // 32KB; wave w privately owns rows w*32..w*32+31

  const int t    = threadIdx.x;
  const int lane = t & 63;
  const int w    = t >> 6;
  const int l15  = lane & 15;
  const int g    = lane >> 4;
  const int n_base = w * 32;           // this wave's sample rows
  const int tile = blockIdx.x;

  // stage this wave's 32 samples of x -> Hbuf (fp32 -> bf16), 8-feat chunks, swizzled
  const float* xt = x + (size_t)tile * TILE * 64 + (size_t)n_base * 64;
#pragma unroll
  for (int i = 0; i < 4; ++i) {
    int f2 = lane + 64 * i;            // chunk id 0..255 (s_local*8 + c)
    int s = f2 >> 3, c = f2 & 7;
    const floatx4* src = (const floatx4*)(xt + f2 * 8);
    floatx4 lo = src[0], hi = src[1];
    bf16x8 v;
    v[0] = (__bf16)lo[0]; v[1] = (__bf16)lo[1]; v[2] = (__bf16)lo[2]; v[3] = (__bf16)lo[3];
    v[4] = (__bf16)hi[0]; v[5] = (__bf16)hi[1]; v[6] = (__bf16)hi[2]; v[7] = (__bf16)hi[3];
    Hbuf[(n_base + s) * 16 + (c ^ (s & 7))] = v;   // (n_base+s)&7 == s&7
  }
  // no barrier: this wave's DS writes are ordered before its DS reads

  floatx4 acc[8][2];

  // ---- layer 0: K=64 ----
  zero_acc(acc);
  layer_mm<2>(wimg, Hbuf, acc, n_base, l15, g, lane);
  write_h((bf16x4*)Hbuf, acc, n_base, l15, g);

  // ---- layers 1..4: K=128 ----
  constexpr int WOFF[5] = {1024, 3072, 5120, 7168, 9216};
#pragma unroll
  for (int l = 0; l < 4; ++l) {
    zero_acc(acc);
    layer_mm<4>(wimg + WOFF[l], Hbuf, acc, n_base, l15, g, lane);
    write_h((bf16x4*)Hbuf, acc, n_base, l15, g);
  }

  // ---- layer 5: M=16, K=128, no relu, + bias, store fp32 ----
  floatx4 a5[2];
  {
    floatx4 z = {0.f, 0.f, 0.f, 0.f};
    a5[0] = z; a5[1] = z;
  }
#pragma unroll
  for (int kt = 0; kt < 4; ++kt) {
    int cx = (kt * 4 + g) ^ (l15 & 7);
    bf16x8 a = wimg[9216 + (kt << 6) + lane];        // W5^T, coalesced
#pragma unroll
    for (int nt = 0; nt < 2; ++nt) {
      bf16x8 b = Hbuf[(n_base + 16 * nt + l15) * 16 + cx];
      a5[nt] = __builtin_amdgcn_mfma_f32_16x16x32_bf16(a, b, a5[nt], 0, 0, 0);
    }
  }
  floatx4 bv = *(const floatx4*)(bias + 4 * g);
  floatx4* outv = (floatx4*)out;
#pragma unroll
  for (int nt = 0; nt < 2; ++nt) {
    int s = tile * TILE + n_base + 16 * nt + l15;
    outv[s * 4 + g] = a5[nt] + bv;     // wave's stores cover contiguous 1KB
  }
}

extern "C" void kernel_launch(void* const* d_in, const int* in_sizes, int n_in,
                              void* d_out, int out_size, void* d_ws, size_t ws_size,
                              hipStream_t stream) {
  (void)in_sizes; (void)n_in; (void)out_size; (void)ws_size;
  const float* x    = (const float*)d_in[0];
  const float* W0   = (const float*)d_in[1];
  const float* W1   = (const float*)d_in[2];
  const float* W2   = (const float*)d_in[3];
  const float* W3   = (const float*)d_in[4];
  const float* W4   = (const float*)d_in[5];
  const float* W5   = (const float*)d_in[6];
  const float* bias = (const float*)d_in[7];
  bf16x8* ws = (bf16x8*)d_ws;   // needs 151552 B

  prep_weights<<<(WTOT + 255) / 256, 256, 0, stream>>>(W0, W1, W2, W3, W4, W5, ws);
  mlp_kernel<<<NBLK, 256, 0, stream>>>(x, bias, (const bf16x8*)ws, (float*)d_out);
}

// Round 4
// 280.149 us; speedup vs baseline: 1.0090x; 1.0010x over previous
//
#include <hip/hip_runtime.h>
#include <stdint.h>

// MLP_tcnn: x(524288x64) -> [W0 64x128 relu] -> [W1..W4 128x128 relu] -> [W5 128x16] + bias
// R4: 32x32x16 MFMA (half the MFMA instrs vs 16x16x32), 64 samples/wave (halves
// per-sample mem ops), explicit kstep-level double-buffer of A(global)/B(LDS) so
// each wave overlaps loads of kstep+1 with MFMAs of kstep.  Barrier-free: wave
// owns 64 samples end-to-end, H round-trips through its private 16KB LDS slice.
// A read from lane-ordered global image (coalesced 1KB/instr, L1/L2-resident).

typedef __bf16 bf16x8 __attribute__((ext_vector_type(8)));
typedef __bf16 bf16x4 __attribute__((ext_vector_type(4)));
typedef float  floatx4  __attribute__((ext_vector_type(4)));
typedef float  floatx16 __attribute__((ext_vector_type(16)));

constexpr int NS   = 524288;
constexpr int SPW  = 64;            // samples per wave
constexpr int WPB  = 4;             // waves per block
constexpr int TILE = SPW * WPB;     // 256 samples per block
constexpr int NBLK = NS / TILE;     // 2048

// weight image: per layer, groups of 64 chunks indexed (ks*MT + mt); chunk at
// lane l = W^T[row = mt*32 + (l&31)][k = 16*ks + 8*(l>>5) + j], j=0..7.
// L0: KS=4,MT=4 -> 1024 chunks | L1-4: KS=8,MT=4 -> 2048 ea | L5: KS=8,MT=1 (rows padded to 32) -> 512
constexpr int WTOT = 9728;          // 155648 bytes in d_ws

__global__ void prep_weights(const float* __restrict__ W0, const float* __restrict__ W1,
                             const float* __restrict__ W2, const float* __restrict__ W3,
                             const float* __restrict__ W4, const float* __restrict__ W5,
                             bf16x8* __restrict__ ws) {
  int gid = blockIdx.x * blockDim.x + threadIdx.x;
  if (gid >= WTOT) return;
  const float* Wsrc; int nout, MT, base;
  if (gid < 1024)      { Wsrc = W0; nout = 128; MT = 4; base = 0;    }
  else if (gid < 3072) { Wsrc = W1; nout = 128; MT = 4; base = 1024; }
  else if (gid < 5120) { Wsrc = W2; nout = 128; MT = 4; base = 3072; }
  else if (gid < 7168) { Wsrc = W3; nout = 128; MT = 4; base = 5120; }
  else if (gid < 9216) { Wsrc = W4; nout = 128; MT = 4; base = 7168; }
  else                 { Wsrc = W5; nout = 16;  MT = 1; base = 9216; }
  int id  = gid - base;
  int l   = id & 63, blk = id >> 6;
  int mt  = blk % MT, ks = blk / MT;
  int row = mt * 32 + (l & 31);       // out-feature (A m-index)
  int k0  = ks * 16 + (l >> 5) * 8;   // in-feature base (A k-index)
  bf16x8 v;
#pragma unroll
  for (int j = 0; j < 8; ++j)
    v[j] = (row < nout) ? (__bf16)Wsrc[(k0 + j) * nout + row] : (__bf16)0.0f;
  ws[gid] = v;
}

// B-frag read: lane (h=l>>5, n31=l&31) needs H[sample nt*32+n31][feats 16ks+8h..+7]
__device__ __forceinline__ bf16x8 h_read(const bf16x8* Hw, int nt, int ks, int n31, int h) {
  int c = 2 * ks + h;
  int row = nt * 32 + n31;
  return Hw[row * 16 + (c ^ (n31 & 7))];
}

// one layer: 128 out x 64 samples per wave. A from global image, B from private LDS.
// kstep-level double buffer: loads for ks+1 issued before MFMAs of ks.
template <int KS>
__device__ __forceinline__ void layer_mm(const bf16x8* __restrict__ wg,
                                         const bf16x8* Hw, floatx16 acc[2][4],
                                         int l, int n31, int h) {
  bf16x8 a_cur[4], b_cur[2];
#pragma unroll
  for (int mt = 0; mt < 4; ++mt) a_cur[mt] = wg[mt * 64 + l];
  b_cur[0] = h_read(Hw, 0, 0, n31, h);
  b_cur[1] = h_read(Hw, 1, 0, n31, h);
#pragma unroll
  for (int ks = 0; ks < KS; ++ks) {
    bf16x8 a_nxt[4], b_nxt[2];
    if (ks + 1 < KS) {
#pragma unroll
      for (int mt = 0; mt < 4; ++mt) a_nxt[mt] = wg[((ks + 1) * 4 + mt) * 64 + l];
      b_nxt[0] = h_read(Hw, 0, ks + 1, n31, h);
      b_nxt[1] = h_read(Hw, 1, ks + 1, n31, h);
    }
#pragma unroll
    for (int nt = 0; nt < 2; ++nt)
#pragma unroll
      for (int mt = 0; mt < 4; ++mt)
        acc[nt][mt] = __builtin_amdgcn_mfma_f32_32x32x16_bf16(a_cur[mt], b_cur[nt], acc[nt][mt], 0, 0, 0);
    if (ks + 1 < KS) {
#pragma unroll
      for (int mt = 0; mt < 4; ++mt) a_cur[mt] = a_nxt[mt];
      b_cur[0] = b_nxt[0]; b_cur[1] = b_nxt[1];
    }
  }
}

__device__ __forceinline__ void zero_acc(floatx16 acc[2][4]) {
#pragma unroll
  for (int nt = 0; nt < 2; ++nt)
#pragma unroll
    for (int mt = 0; mt < 4; ++mt)
#pragma unroll
      for (int r = 0; r < 16; ++r) acc[nt][mt][r] = 0.0f;
}

// C(32x32) frag: col = n31, row = (r&3) + 8*(r>>2) + 4h.  relu -> bf16 -> H sample-major.
__device__ __forceinline__ void write_h(bf16x4* H8, const floatx16 acc[2][4],
                                        int n31, int h) {
#pragma unroll
  for (int nt = 0; nt < 2; ++nt) {
    int row_s = nt * 32 + n31;
#pragma unroll
    for (int mt = 0; mt < 4; ++mt)
#pragma unroll
      for (int q = 0; q < 4; ++q) {
        bf16x4 v;
#pragma unroll
        for (int j = 0; j < 4; ++j) v[j] = (__bf16)fmaxf(acc[nt][mt][4 * q + j], 0.0f);
        int c = 4 * mt + q;                              // feat chunk (feats 32mt+8q+4h+j live in half h)
        H8[row_s * 32 + (c ^ (n31 & 7)) * 2 + h] = v;
      }
  }
}

__global__ void __launch_bounds__(256, 2) mlp_kernel(const float* __restrict__ x,
                                                     const float* __restrict__ bias,
                                                     const bf16x8* __restrict__ wimg,
                                                     float* __restrict__ out) {
  __shared__ bf16x8 Hbuf[WPB * 64 * 16];   // 64KB; wave w privately owns its 16KB slice

  const int t   = threadIdx.x;
  const int l   = t & 63;
  const int w   = t >> 6;
  const int n31 = l & 31;
  const int h   = l >> 5;
  bf16x8* Hw = Hbuf + w * (64 * 16);
  const size_t S0 = (size_t)blockIdx.x * TILE + (size_t)w * SPW;

  // stage this wave's 64 samples of x -> Hw (fp32 -> bf16), 8-feat chunks, swizzled
  const float* xw = x + S0 * 64;
#pragma unroll
  for (int it = 0; it < 8; ++it) {
    int id = it * 64 + l, s = id >> 3, c = id & 7;
    const floatx4* p = (const floatx4*)(xw + id * 8);
    floatx4 lo = p[0], hi = p[1];
    bf16x8 v;
    v[0] = (__bf16)lo[0]; v[1] = (__bf16)lo[1]; v[2] = (__bf16)lo[2]; v[3] = (__bf16)lo[3];
    v[4] = (__bf16)hi[0]; v[5] = (__bf16)hi[1]; v[6] = (__bf16)hi[2]; v[7] = (__bf16)hi[3];
    Hw[s * 16 + (c ^ (s & 7))] = v;
  }
  // no barrier: wave-private rows, per-wave DS ordering

  floatx16 acc[2][4];

  // ---- layer 0: K=64 ----
  zero_acc(acc);
  layer_mm<4>(wimg, Hw, acc, l, n31, h);
  write_h((bf16x4*)Hw, acc, n31, h);

  // ---- layers 1..4: K=128 ----
  constexpr int WOFF[4] = {1024, 3072, 5120, 7168};
#pragma unroll
  for (int ly = 0; ly < 4; ++ly) {
    zero_acc(acc);
    layer_mm<8>(wimg + WOFF[ly], Hw, acc, l, n31, h);
    write_h((bf16x4*)Hw, acc, n31, h);
  }

  // ---- layer 5: M=16 (padded to 32 with zero rows), K=128, no relu, +bias ----
  floatx16 a5[2];
#pragma unroll
  for (int nt = 0; nt < 2; ++nt)
#pragma unroll
    for (int r = 0; r < 16; ++r) a5[nt][r] = 0.0f;

  {
    const bf16x8* wg5 = wimg + 9216;
    bf16x8 a_cur = wg5[l];
    bf16x8 b_cur[2] = {h_read(Hw, 0, 0, n31, h), h_read(Hw, 1, 0, n31, h)};
#pragma unroll
    for (int ks = 0; ks < 8; ++ks) {
      bf16x8 a_nxt; bf16x8 b_nxt[2];
      if (ks + 1 < 8) {
        a_nxt = wg5[(ks + 1) * 64 + l];
        b_nxt[0] = h_read(Hw, 0, ks + 1, n31, h);
        b_nxt[1] = h_read(Hw, 1, ks + 1, n31, h);
      }
      a5[0] = __builtin_amdgcn_mfma_f32_32x32x16_bf16(a_cur, b_cur[0], a5[0], 0, 0, 0);
      a5[1] = __builtin_amdgcn_mfma_f32_32x32x16_bf16(a_cur, b_cur[1], a5[1], 0, 0, 0);
      if (ks + 1 < 8) { a_cur = a_nxt; b_cur[0] = b_nxt[0]; b_cur[1] = b_nxt[1]; }
    }
  }

  // valid rows (<16) are reg groups q=0,1: row = j + 8q + 4h
  floatx4 bv0 = *(const floatx4*)(bias + 4 * h);        // feats 4h..4h+3   (q=0)
  floatx4 bv1 = *(const floatx4*)(bias + 8 + 4 * h);    // feats 8+4h..+3   (q=1)
  floatx4* outv = (floatx4*)out;
#pragma unroll
  for (int nt = 0; nt < 2; ++nt) {
    size_t s = S0 + nt * 32 + n31;
    floatx4 o0, o1;
#pragma unroll
    for (int j = 0; j < 4; ++j) { o0[j] = a5[nt][j] + bv0[j]; o1[j] = a5[nt][4 + j] + bv1[j]; }
    outv[s * 4 + h]     = o0;   // feats 4h..4h+3
    outv[s * 4 + 2 + h] = o1;   // feats 8+4h..11+4h
  }
}

extern "C" void kernel_launch(void* const* d_in, const int* in_sizes, int n_in,
                              void* d_out, int out_size, void* d_ws, size_t ws_size,
                              hipStream_t stream) {
  (void)in_sizes; (void)n_in; (void)out_size; (void)ws_size;
  const float* x    = (const float*)d_in[0];
  const float* W0   = (const float*)d_in[1];
  const float* W1   = (const float*)d_in[2];
  const float* W2   = (const float*)d_in[3];
  const float* W3   = (const float*)d_in[4];
  const float* W4   = (const float*)d_in[5];
  const float* W5   = (const float*)d_in[6];
  const float* bias = (const float*)d_in[7];
  bf16x8* ws = (bf16x8*)d_ws;   // needs 155648 B

  prep_weights<<<(WTOT + 255) / 256, 256, 0, stream>>>(W0, W1, W2, W3, W4, W5, ws);
  mlp_kernel<<<NBLK, 256, 0, stream>>>(x, bias, (const bf16x8*)ws, (float*)d_out);
}

// Round 5
// 270.195 us; speedup vs baseline: 1.0462x; 1.0368x over previous
//
#include <hip/hip_runtime.h>
#include <stdint.h>

// MLP_tcnn: x(524288x64) -> [W0 64x128 relu] -> [W1..W4 128x128 relu] -> [W5 128x16] + bias
// R5: ZERO-LDS, ZERO-BARRIER, H-IN-REGISTERS. Each wave owns 64 samples end-to-end.
// Per layer: H_next^T = W^T * H^T with mfma_f32_32x32x16_bf16; acc (C-layout) is
// converted to next layer's B-operand ENTIRELY IN REGISTERS: relu+pack to bf16
// quads + one __shfl_xor(.,32) per quad-pair (C and B share the sample->lane map;
// only a half-wave row permutation differs).  A (weights) streamed from a
// lane-ordered global image with kstep double-buffering, and each layer's ks=0
// frags are issued BEFORE the previous layer's epilogue (weights are static ->
// prefetch has no dependencies).  No __shared__ at all.

typedef __bf16 bf16x8 __attribute__((ext_vector_type(8)));
typedef __bf16 bf16x4 __attribute__((ext_vector_type(4)));
typedef float  floatx4  __attribute__((ext_vector_type(4)));
typedef float  floatx16 __attribute__((ext_vector_type(16)));

constexpr int NS   = 524288;
constexpr int SPW  = 64;            // samples per wave
constexpr int WPB  = 4;             // waves per block (independent)
constexpr int TILE = SPW * WPB;     // 256 samples per block
constexpr int NBLK = NS / TILE;     // 2048

// weight image (same as R4): per layer, groups of 64 chunks indexed (ks*MT + mt);
// chunk at lane l = W^T[row = mt*32 + (l&31)][k = 16*ks + 8*(l>>5) + j], j=0..7.
// L0: KS=4,MT=4 -> 1024 | L1-4: KS=8,MT=4 -> 2048 ea | L5: KS=8,MT=1 (rows padded to 32) -> 512
constexpr int WTOT = 9728;          // 155648 bytes in d_ws

__global__ void prep_weights(const float* __restrict__ W0, const float* __restrict__ W1,
                             const float* __restrict__ W2, const float* __restrict__ W3,
                             const float* __restrict__ W4, const float* __restrict__ W5,
                             bf16x8* __restrict__ ws) {
  int gid = blockIdx.x * blockDim.x + threadIdx.x;
  if (gid >= WTOT) return;
  const float* Wsrc; int nout, MT, base;
  if (gid < 1024)      { Wsrc = W0; nout = 128; MT = 4; base = 0;    }
  else if (gid < 3072) { Wsrc = W1; nout = 128; MT = 4; base = 1024; }
  else if (gid < 5120) { Wsrc = W2; nout = 128; MT = 4; base = 3072; }
  else if (gid < 7168) { Wsrc = W3; nout = 128; MT = 4; base = 5120; }
  else if (gid < 9216) { Wsrc = W4; nout = 128; MT = 4; base = 7168; }
  else                 { Wsrc = W5; nout = 16;  MT = 1; base = 9216; }
  int id  = gid - base;
  int l   = id & 63, blk = id >> 6;
  int mt  = blk % MT, ks = blk / MT;
  int row = mt * 32 + (l & 31);
  int k0  = ks * 16 + (l >> 5) * 8;
  bf16x8 v;
#pragma unroll
  for (int j = 0; j < 8; ++j)
    v[j] = (row < nout) ? (__bf16)Wsrc[(k0 + j) * nout + row] : (__bf16)0.0f;
  ws[gid] = v;
}

union Q8 { bf16x4 v; int u[2]; };

// C(32x32 tile)->B conversion: acc[nt][mt] reg r holds H[sample nt*32+n31]
// [feat 32mt + (r&3) + 8*(r>>2) + 4h].  B-frag b[nt][ks][j] (lane n31,h) =
// H[sample][feat 16ks+8h+j].  Quad q (regs 4q..4q+3) of half h_src supplies
// j = 4*h_src + i of ks = 2mt + (q>>1), consumed by half h_dst = q&1.
// => per quad-pair one shfl_xor(32): lane h sends quad[2qp + (1-h)], keeps quad[2qp+h].
__device__ __forceinline__ void tile_to_b(const floatx16 v, bf16x8 b[/*2 per tile*/],
                                          int mt, int h, bf16x8* bdst_nt /* &b[nt][0] */) {
  bf16x4 quad[4];
#pragma unroll
  for (int q = 0; q < 4; ++q)
#pragma unroll
    for (int i = 0; i < 4; ++i)
      quad[q][i] = (__bf16)fmaxf(v[4 * q + i], 0.0f);
#pragma unroll
  for (int qp = 0; qp < 2; ++qp) {
    bf16x4 keep = h ? quad[2 * qp + 1] : quad[2 * qp];
    Q8 s; s.v = h ? quad[2 * qp] : quad[2 * qp + 1];
    Q8 r;
    r.u[0] = __shfl_xor(s.u[0], 32, 64);
    r.u[1] = __shfl_xor(s.u[1], 32, 64);
    bf16x4 low  = h ? r.v : keep;   // j = 0..3 (from h_src = 0)
    bf16x4 high = h ? keep : r.v;   // j = 4..7 (from h_src = 1)
    bf16x8 bb;
#pragma unroll
    for (int i = 0; i < 4; ++i) { bb[i] = low[i]; bb[4 + i] = high[i]; }
    bdst_nt[2 * mt + qp] = bb;
  }
}

__device__ __forceinline__ void zero_acc(floatx16 acc[2][4]) {
#pragma unroll
  for (int nt = 0; nt < 2; ++nt)
#pragma unroll
    for (int mt = 0; mt < 4; ++mt)
#pragma unroll
      for (int r = 0; r < 16; ++r) acc[nt][mt][r] = 0.0f;
}

// one layer: 128 out x 64 samples.  a[0][*] must hold this layer's ks=0 frags on
// entry; on exit a[0][*] holds wg_next's ks=0 frags (prefetched before epilogue).
template <int KS>
__device__ __forceinline__ void layer_mm(const bf16x8* __restrict__ wg,
                                         const bf16x8* __restrict__ wg_next,
                                         bf16x8 a[2][4], const bf16x8 b[2][8],
                                         floatx16 acc[2][4], int l) {
#pragma unroll
  for (int ks = 0; ks < KS; ++ks) {
    const int cur = ks & 1, nxt = cur ^ 1;
    if (ks + 1 < KS) {
#pragma unroll
      for (int mt = 0; mt < 4; ++mt) a[nxt][mt] = wg[((ks + 1) * 4 + mt) * 64 + l];
    } else {
#pragma unroll
      for (int mt = 0; mt < 4; ++mt) a[nxt][mt] = wg_next[mt * 64 + l];
    }
#pragma unroll
    for (int nt = 0; nt < 2; ++nt)
#pragma unroll
      for (int mt = 0; mt < 4; ++mt)
        acc[nt][mt] = __builtin_amdgcn_mfma_f32_32x32x16_bf16(a[cur][mt], b[nt][ks],
                                                              acc[nt][mt], 0, 0, 0);
  }
}

__device__ __forceinline__ void epilogue_to_b(const floatx16 acc[2][4], bf16x8 b[2][8],
                                              int h) {
#pragma unroll
  for (int nt = 0; nt < 2; ++nt)
#pragma unroll
    for (int mt = 0; mt < 4; ++mt)
      tile_to_b(acc[nt][mt], nullptr, mt, h, &b[nt][0]);
}

__global__ void __launch_bounds__(256, 2) mlp_kernel(const float* __restrict__ x,
                                                     const float* __restrict__ bias,
                                                     const bf16x8* __restrict__ wimg,
                                                     float* __restrict__ out) {
  const int t   = threadIdx.x;
  const int l   = t & 63;
  const int w   = t >> 6;
  const int n31 = l & 31;
  const int h   = l >> 5;
  const size_t S0 = (size_t)blockIdx.x * TILE + (size_t)w * SPW;

  bf16x8 a[2][4];
  bf16x8 b[2][8];
  floatx16 acc[2][4];

  // issue L0 ks=0 A-frags immediately (static addresses, nothing to wait on)
#pragma unroll
  for (int mt = 0; mt < 4; ++mt) a[0][mt] = wimg[mt * 64 + l];

  // x -> B-frags for layer 0, straight from global (no LDS): lane (n31,h) reads
  // x[sample nt*32+n31][feats 16ks+8h .. +7] = 2 contiguous float4
  const float* xw = x + S0 * 64;
#pragma unroll
  for (int nt = 0; nt < 2; ++nt)
#pragma unroll
    for (int ks = 0; ks < 4; ++ks) {
      const floatx4* p = (const floatx4*)(xw + (nt * 32 + n31) * 64 + ks * 16 + h * 8);
      floatx4 lo = p[0], hi = p[1];
      bf16x8 v;
#pragma unroll
      for (int i = 0; i < 4; ++i) { v[i] = (__bf16)lo[i]; v[4 + i] = (__bf16)hi[i]; }
      b[nt][ks] = v;
    }

  // ---- layer 0 (K=64, KS=4) ----
  zero_acc(acc);
  layer_mm<4>(wimg, wimg + 1024, a, b, acc, l);   // leaves a[0] = L1 ks0
  epilogue_to_b(acc, b, h);

  // ---- layers 1..4 (K=128, KS=8) ----
  constexpr int WOFF[5] = {1024, 3072, 5120, 7168, 9216};
#pragma unroll
  for (int ly = 0; ly < 4; ++ly) {
    zero_acc(acc);
    layer_mm<8>(wimg + WOFF[ly], wimg + WOFF[ly + 1], a, b, acc, l);
    epilogue_to_b(acc, b, h);
  }

  // ---- layer 5: M=16 (padded to 32), K=128, no relu, +bias ----
  // a[0][0..3] already hold L5 ks=0..3 (prefetched by layer 4); fetch ks=4..7
#pragma unroll
  for (int mt = 0; mt < 4; ++mt) a[1][mt] = wimg[9216 + (4 + mt) * 64 + l];
  floatx16 a5[2];
#pragma unroll
  for (int nt = 0; nt < 2; ++nt)
#pragma unroll
    for (int r = 0; r < 16; ++r) a5[nt][r] = 0.0f;
#pragma unroll
  for (int ks = 0; ks < 8; ++ks) {
    bf16x8 f = a[ks >> 2][ks & 3];
#pragma unroll
    for (int nt = 0; nt < 2; ++nt)
      a5[nt] = __builtin_amdgcn_mfma_f32_32x32x16_bf16(f, b[nt][ks], a5[nt], 0, 0, 0);
  }

  // valid out-feats (<16): reg quads q=0 (feat 4h+i) and q=1 (feat 8+4h+i)
  floatx4 bv0 = *(const floatx4*)(bias + 4 * h);
  floatx4 bv1 = *(const floatx4*)(bias + 8 + 4 * h);
  floatx4* outv = (floatx4*)out;
#pragma unroll
  for (int nt = 0; nt < 2; ++nt) {
    size_t s = S0 + nt * 32 + n31;
    floatx4 o0, o1;
#pragma unroll
    for (int j = 0; j < 4; ++j) { o0[j] = a5[nt][j] + bv0[j]; o1[j] = a5[nt][4 + j] + bv1[j]; }
    outv[s * 4 + h]     = o0;   // feats 4h..4h+3
    outv[s * 4 + 2 + h] = o1;   // feats 8+4h..11+4h
  }
}

extern "C" void kernel_launch(void* const* d_in, const int* in_sizes, int n_in,
                              void* d_out, int out_size, void* d_ws, size_t ws_size,
                              hipStream_t stream) {
  (void)in_sizes; (void)n_in; (void)out_size; (void)ws_size;
  const float* x    = (const float*)d_in[0];
  const float* W0   = (const float*)d_in[1];
  const float* W1   = (const float*)d_in[2];
  const float* W2   = (const float*)d_in[3];
  const float* W3   = (const float*)d_in[4];
  const float* W4   = (const float*)d_in[5];
  const float* W5   = (const float*)d_in[6];
  const float* bias = (const float*)d_in[7];
  bf16x8* ws = (bf16x8*)d_ws;   // needs 155648 B

  prep_weights<<<(WTOT + 255) / 256, 256, 0, stream>>>(W0, W1, W2, W3, W4, W5, ws);
  mlp_kernel<<<NBLK, 256, 0, stream>>>(x, bias, (const bf16x8*)ws, (float*)d_out);
}